// Round 4
// baseline (345.027 us; speedup 1.0000x reference)
//
#include <hip/hip_runtime.h>
#include <math.h>

#define BB   4
#define CC   64
#define KK   64
#define DDim 16
#define HDim 64
#define WDim 64
#define SS   (DDim*HDim*WDim)   /* 65536 */
#define PLANE (HDim*WDim)       /* 4096  */
#define NCH1 256                /* gemm1 s-chunks per batch (chunk = 256) */
#define TOPN 6

// ---------------------------------------------------------------------------
// Kernel 1: depthwise 3x3x3 conv (SAME), direct-global, register-tiled v3.
// Blocks: t=0 -> q, t=1 -> k AND v (shared input window, 2 acc sets).
// grid = 2*4*64*16 = 8192 blocks x 256 threads. Thread tile: 2h x 8w.
// Rolling 2-plane register window: load P(d-1)->A, P(d)->B, then
// FMA(A,dz0) || load P(d+1)->A2, FMA(B,dz1), FMA(A2,dz2).  Halos via __shfl.
// No LDS, no barriers. Weights block-uniform -> SGPRs.
// ---------------------------------------------------------------------------
__global__ __launch_bounds__(256, 3) void conv_qkv3(
    const float* __restrict__ xq, const float* __restrict__ xkv,
    const float* __restrict__ wq, const float* __restrict__ bq,
    const float* __restrict__ wk, const float* __restrict__ bk,
    const float* __restrict__ wv, const float* __restrict__ bv,
    float* __restrict__ qout, float* __restrict__ kout, float* __restrict__ vout)
{
    // bijective XCD swizzle: 8192 blocks / 8 XCDs = 1024 contiguous per XCD;
    // consecutive works = consecutive d of same (b,c) -> L2 reuse of dz overlap
    int bid  = blockIdx.x;
    int work = (bid & 7) * 1024 + (bid >> 3);
    int t    = work >> 12;            // 0: q,  1: k+v
    int rem  = work & 4095;
    int b    = rem >> 10;
    int c    = (rem >> 4) & 63;
    int d    = rem & 15;

    const float* src = (t ? xkv : xq) + (size_t)(b*CC + c) * SS;
    float wA[27], wB[27], bA, bB;
    if (t == 0) {
        #pragma unroll
        for (int i = 0; i < 27; ++i) { wA[i] = wq[c*27 + i]; wB[i] = 0.f; }
        bA = bq[c]; bB = 0.f;
    } else {
        #pragma unroll
        for (int i = 0; i < 27; ++i) { wA[i] = wk[c*27 + i]; wB[i] = wv[c*27 + i]; }
        bA = bk[c]; bB = bv[c];
    }
    float* dA = (t ? kout : qout) + (size_t)(b*CC + c) * SS;
    float* dB = vout + (size_t)(b*CC + c) * SS;

    const int tid  = threadIdx.x;
    const int lane = tid & 63;
    const int wg   = tid & 7;          // w-group within row
    const int w0   = wg << 3;          // 0..56
    const int h0   = (tid >> 3) << 1;  // 0..62 (2-row tile)

    float accA[2][8], accB[2][8];
    #pragma unroll
    for (int i = 0; i < 2; ++i)
        #pragma unroll
        for (int j = 0; j < 8; ++j) { accA[i][j] = bA; accB[i][j] = bB; }

    // window rows gy = h0-1 .. h0+2 ; W[r][1..8] = elems w0..w0+7
#define LOADP(W, p) {                                                          \
    _Pragma("unroll")                                                          \
    for (int r_ = 0; r_ < 4; ++r_) {                                           \
        const int gy_ = h0 - 1 + r_;                                           \
        float4 a0_ = make_float4(0.f,0.f,0.f,0.f), a1_ = a0_;                  \
        if ((p) >= 0 && (p) < DDim && gy_ >= 0 && gy_ < HDim) {                \
            const float* bp_ = src + (p)*PLANE + gy_*WDim + w0;                \
            a0_ = *(const float4*)(bp_);                                       \
            a1_ = *(const float4*)(bp_ + 4);                                   \
        }                                                                      \
        W[r_][1]=a0_.x; W[r_][2]=a0_.y; W[r_][3]=a0_.z; W[r_][4]=a0_.w;        \
        W[r_][5]=a1_.x; W[r_][6]=a1_.y; W[r_][7]=a1_.z; W[r_][8]=a1_.w;        \
    } }

#define HALOP(W) {                                                             \
    _Pragma("unroll")                                                          \
    for (int r_ = 0; r_ < 4; ++r_) {                                           \
        float lh_ = __shfl(W[r_][8], lane - 1, 64);                            \
        float rh_ = __shfl(W[r_][1], lane + 1, 64);                            \
        W[r_][0] = (wg > 0) ? lh_ : 0.f;                                       \
        W[r_][9] = (wg < 7) ? rh_ : 0.f;                                       \
    } }

#define FMAP(W, dz) {                                                          \
    _Pragma("unroll")                                                          \
    for (int dy_ = 0; dy_ < 3; ++dy_) {                                        \
        const float ca0_ = wA[(dz)*9 + dy_*3 + 0];                             \
        const float ca1_ = wA[(dz)*9 + dy_*3 + 1];                             \
        const float ca2_ = wA[(dz)*9 + dy_*3 + 2];                             \
        const float cb0_ = wB[(dz)*9 + dy_*3 + 0];                             \
        const float cb1_ = wB[(dz)*9 + dy_*3 + 1];                             \
        const float cb2_ = wB[(dz)*9 + dy_*3 + 2];                             \
        _Pragma("unroll")                                                      \
        for (int i_ = 0; i_ < 2; ++i_) {                                       \
            _Pragma("unroll")                                                  \
            for (int j_ = 0; j_ < 8; ++j_) {                                   \
                float sA_ = fmaf(ca0_, W[i_+dy_][j_],   accA[i_][j_]);         \
                sA_       = fmaf(ca1_, W[i_+dy_][j_+1], sA_);                  \
                accA[i_][j_] = fmaf(ca2_, W[i_+dy_][j_+2], sA_);               \
                if (t) {                                                       \
                    float sB_ = fmaf(cb0_, W[i_+dy_][j_],   accB[i_][j_]);     \
                    sB_       = fmaf(cb1_, W[i_+dy_][j_+1], sB_);              \
                    accB[i_][j_] = fmaf(cb2_, W[i_+dy_][j_+2], sB_);           \
                }                                                              \
            }                                                                  \
        }                                                                      \
    } }

    float WA[4][10], WB2[4][10], WC[4][10];
    LOADP(WA, d - 1);          // plane d-1
    LOADP(WB2, d);             // plane d
    LOADP(WC, d + 1);          // plane d+1 (issued before any FMA)
    HALOP(WA);
    FMAP(WA, 0);
    HALOP(WB2);
    FMAP(WB2, 1);
    HALOP(WC);
    FMAP(WC, 2);

#undef LOADP
#undef HALOP
#undef FMAP

    #pragma unroll
    for (int i = 0; i < 2; ++i) {
        const int off = d*PLANE + (h0 + i)*WDim + w0;
        *(float4*)&dA[off]   = make_float4(accA[i][0],accA[i][1],accA[i][2],accA[i][3]);
        *(float4*)&dA[off+4] = make_float4(accA[i][4],accA[i][5],accA[i][6],accA[i][7]);
        if (t) {
            *(float4*)&dB[off]   = make_float4(accB[i][0],accB[i][1],accB[i][2],accB[i][3]);
            *(float4*)&dB[off+4] = make_float4(accB[i][4],accB[i][5],accB[i][6],accB[i][7]);
        }
    }
}

// ---------------------------------------------------------------------------
// Kernel 2: attn partials. Per block: one batch, one 256-s chunk.
// LDS tiles stored [s][c] (pad 68) so inner loop reads are uniform-row
// ds_read_b128 (conflict-free broadcast groups). 128 threads, 4x8 per thread.
// ---------------------------------------------------------------------------
__global__ __launch_bounds__(128) void gemm1_qk(
    const float* __restrict__ q, const float* __restrict__ kk, float* __restrict__ part)
{
    __shared__ float qt[64][68];
    __shared__ float kt[64][68];
    int bid = blockIdx.x;
    int b  = bid >> 8;
    int ch = bid & 255;
    int tid = threadIdx.x;
    const float* qb = q  + (size_t)b*CC*SS;
    const float* kb = kk + (size_t)b*KK*SS;
    int c0  = (tid >> 3) * 4;     // 0..60
    int k0  = (tid & 7) * 8;      // 0..56
    int ls4 = (tid & 15) * 4;     // loader: s offset
    int lcg = tid >> 4;           // loader: c group 0..7
    float acc[4][8] = {};
    int sbase0 = ch * 256;
    for (int st = 0; st < 4; ++st) {
        int sb = sbase0 + st*64;
        __syncthreads();
        #pragma unroll
        for (int i = 0; i < 8; ++i) {
            int cc2 = lcg*8 + i;
            float4 qv = *(const float4*)&qb[cc2*SS + sb + ls4];
            float4 kv = *(const float4*)&kb[cc2*SS + sb + ls4];
            qt[ls4+0][cc2] = qv.x; qt[ls4+1][cc2] = qv.y; qt[ls4+2][cc2] = qv.z; qt[ls4+3][cc2] = qv.w;
            kt[ls4+0][cc2] = kv.x; kt[ls4+1][cc2] = kv.y; kt[ls4+2][cc2] = kv.z; kt[ls4+3][cc2] = kv.w;
        }
        __syncthreads();
        #pragma unroll 8
        for (int s = 0; s < 64; ++s) {
            float4 a  = *(const float4*)&qt[s][c0];
            float4 b0 = *(const float4*)&kt[s][k0];
            float4 b1 = *(const float4*)&kt[s][k0+4];
            float av[4] = {a.x, a.y, a.z, a.w};
            float bv[8] = {b0.x,b0.y,b0.z,b0.w,b1.x,b1.y,b1.z,b1.w};
            #pragma unroll
            for (int i = 0; i < 4; ++i)
                #pragma unroll
                for (int j = 0; j < 8; ++j)
                    acc[i][j] = fmaf(av[i], bv[j], acc[i][j]);
        }
    }
    float* pb = part + (size_t)(b*NCH1 + ch)*(CC*KK);
    #pragma unroll
    for (int i = 0; i < 4; ++i) {
        *(float4*)&pb[(c0+i)*KK + k0]     = make_float4(acc[i][0],acc[i][1],acc[i][2],acc[i][3]);
        *(float4*)&pb[(c0+i)*KK + k0 + 4] = make_float4(acc[i][4],acc[i][5],acc[i][6],acc[i][7]);
    }
}

// ---------------------------------------------------------------------------
// Kernel 3: reduce 256 chunk-partials -> attn logits (scaled 1/sqrt(K)=0.125)
// ---------------------------------------------------------------------------
__global__ __launch_bounds__(256) void reduce_attn(
    const float* __restrict__ part, float* __restrict__ attn)
{
    int bid = blockIdx.x;            // b*64 + c
    int b = bid >> 6, c = bid & 63;
    int tid = threadIdx.x;
    int k = tid & 63, g = tid >> 6;
    float s = 0.f;
    for (int ch = g; ch < NCH1; ch += 4)
        s += part[(size_t)(b*NCH1 + ch)*(CC*KK) + c*KK + k];
    __shared__ float red[256];
    red[tid] = s;
    __syncthreads();
    if (tid < 64) {
        float tot = red[tid] + red[tid+64] + red[tid+128] + red[tid+192];
        attn[b*CC*KK + c*KK + tid] = tot * 0.125f;
    }
}

// ---------------------------------------------------------------------------
// Kernel 4: per-batch softmax over K (rows) + top-6 mask per column over C.
// Strict ">" selection == lax.top_k lowest-index-first tie break. Writes
// attn_m (output 1) which gemm2 consumes.
// ---------------------------------------------------------------------------
__global__ __launch_bounds__(64) void softmax_topk(
    const float* __restrict__ attn, float* __restrict__ attn_m)
{
    __shared__ float p[64*65];
    int b = blockIdx.x;
    int t = threadIdx.x;
    for (int i = 0; i < 64; ++i) p[i*65 + t] = attn[b*4096 + i*64 + t];
    __syncthreads();
    // row softmax (row = t)
    float m = -1e30f;
    for (int k = 0; k < 64; ++k) m = fmaxf(m, p[t*65 + k]);
    float sum = 0.f;
    for (int k = 0; k < 64; ++k) { float e = expf(p[t*65+k] - m); p[t*65+k] = e; sum += e; }
    float inv = 1.f / sum;
    for (int k = 0; k < 64; ++k) p[t*65+k] *= inv;
    __syncthreads();
    // top-6 per column (column = t)
    unsigned long long chosen = 0ull;
    #pragma unroll
    for (int pass = 0; pass < TOPN; ++pass) {
        float best = -1.f; int bi = 0;
        for (int c2 = 0; c2 < 64; ++c2) {
            float v = p[c2*65 + t];
            if (!((chosen >> c2) & 1ull) && v > best) { best = v; bi = c2; }
        }
        chosen |= 1ull << bi;
    }
    for (int c2 = 0; c2 < 64; ++c2) {
        float v = p[c2*65 + t];
        attn_m[b*4096 + c2*64 + t] = ((chosen >> c2) & 1ull) ? v : 0.f;
    }
}

// ---------------------------------------------------------------------------
// Kernel 5: out = x_q + attn_m @ v. Per block: one batch, 512-s chunk
// (4 subtiles of 128). attn_m held transposed [k][c] in LDS for b128 reads.
// ---------------------------------------------------------------------------
__global__ __launch_bounds__(256) void gemm2_out(
    const float* __restrict__ attn_m, const float* __restrict__ v,
    const float* __restrict__ xq, float* __restrict__ out)
{
    __shared__ float amt[64][68];    // [k][c]
    __shared__ float vt[64][132];    // [k][s]
    int bid = blockIdx.x;
    int b  = bid >> 7;
    int ch = bid & 127;
    int tid = threadIdx.x;
    for (int i = 0; i < 16; ++i) {
        int idx = i*256 + tid;                 // idx = c*64 + k
        amt[idx & 63][idx >> 6] = attn_m[b*4096 + idx];
    }
    int c0 = (tid >> 4) * 4;      // 0..60
    int s0 = (tid & 15) * 8;      // 0..120
    const float* vb = v  + (size_t)b*KK*SS;
    const float* xb = xq + (size_t)b*CC*SS;
    float* ob = out + (size_t)b*CC*SS;
    int sb0 = ch * 512;
    for (int st = 0; st < 4; ++st) {
        int sb = sb0 + st*128;
        __syncthreads();
        #pragma unroll
        for (int i = 0; i < 8; ++i) {
            int k  = (tid >> 5)*8 + i;
            int s4 = (tid & 31)*4;
            *(float4*)&vt[k][s4] = *(const float4*)&vb[k*SS + sb + s4];
        }
        __syncthreads();
        float acc[4][8] = {};
        #pragma unroll 8
        for (int k = 0; k < 64; ++k) {
            float4 a  = *(const float4*)&amt[k][c0];
            float4 v0 = *(const float4*)&vt[k][s0];
            float4 v1 = *(const float4*)&vt[k][s0+4];
            float av[4] = {a.x,a.y,a.z,a.w};
            float vv[8] = {v0.x,v0.y,v0.z,v0.w,v1.x,v1.y,v1.z,v1.w};
            #pragma unroll
            for (int i = 0; i < 4; ++i)
                #pragma unroll
                for (int j = 0; j < 8; ++j)
                    acc[i][j] = fmaf(av[i], vv[j], acc[i][j]);
        }
        #pragma unroll
        for (int i = 0; i < 4; ++i) {
            int off = (c0+i)*SS + sb + s0;
            float4 x0 = *(const float4*)&xb[off];
            float4 x1 = *(const float4*)&xb[off+4];
            *(float4*)&ob[off]   = make_float4(acc[i][0]+x0.x, acc[i][1]+x0.y,
                                               acc[i][2]+x0.z, acc[i][3]+x0.w);
            *(float4*)&ob[off+4] = make_float4(acc[i][4]+x1.x, acc[i][5]+x1.y,
                                               acc[i][6]+x1.z, acc[i][7]+x1.w);
        }
    }
}

// ---------------------------------------------------------------------------
extern "C" void kernel_launch(void* const* d_in, const int* in_sizes, int n_in,
                              void* d_out, int out_size, void* d_ws, size_t ws_size,
                              hipStream_t stream)
{
    const float* xq  = (const float*)d_in[0];
    const float* xkv = (const float*)d_in[1];
    const float* wq  = (const float*)d_in[2];
    const float* bq  = (const float*)d_in[3];
    const float* wk  = (const float*)d_in[4];
    const float* bk  = (const float*)d_in[5];
    const float* wv  = (const float*)d_in[6];
    const float* bv  = (const float*)d_in[7];
    float* out = (float*)d_out;

    // workspace: k, v, gemm1 partials, attn logits  (~145 MiB)
    float* k_ws = (float*)d_ws;
    float* v_ws = k_ws + (size_t)BB*KK*SS;
    float* part = v_ws + (size_t)BB*KK*SS;
    float* attn = part + (size_t)BB*NCH1*CC*KK;

    float* q_store = out;                        // q lives in output-0 region,
                                                 // overwritten by gemm2_out
    float* attn_m  = out + (size_t)BB*CC*SS;     // output 1 (B*C*K floats)

    conv_qkv3  <<<2*BB*CC*DDim, 256, 0, stream>>>(xq, xkv, wq, bq, wk, bk, wv, bv,
                                                  q_store, k_ws, v_ws);
    gemm1_qk   <<<BB*NCH1,   128, 0, stream>>>(q_store, k_ws, part);
    reduce_attn<<<BB*CC,     256, 0, stream>>>(part, attn);
    softmax_topk<<<BB,        64, 0, stream>>>(attn, attn_m);
    gemm2_out  <<<BB*128,    256, 0, stream>>>(attn_m, v_ws, xq, out);
}